// Round 3
// baseline (461.120 us; speedup 1.0000x reference)
//
#include <hip/hip_runtime.h>
#include <stdint.h>

#define B_  8
#define C_  512
#define H_  96
#define W_  96
#define CQ_ 64
#define P_  (H_*W_)     // 9216 pixels per batch
#define NP  (B_*P_)     // 73728
#define L_  (W_+H_)     // 192 logits per pixel

typedef __attribute__((ext_vector_type(8))) short short8;
typedef __attribute__((ext_vector_type(4))) float f32x4;
typedef __attribute__((ext_vector_type(4))) unsigned short us4;

__device__ __forceinline__ ushort f2bf(float f) {
    uint32_t u = __builtin_bit_cast(uint32_t, f);
    u += 0x7fff + ((u >> 16) & 1);
    return (ushort)(u >> 16);
}
__device__ __forceinline__ float bf2f(ushort h) {
    uint32_t u = ((uint32_t)h) << 16;
    return __builtin_bit_cast(float, u);
}

// global -> LDS direct 16B copy (dest = wave-uniform base + lane*16)
#define GLL16(g, l) __builtin_amdgcn_global_load_lds( \
    (const __attribute__((address_space(1))) uint32_t*)(g), \
    (__attribute__((address_space(3))) uint32_t*)(l), 16, 0, 0)

// ---------------- K0a: x (b,c,p) fp32 -> x_t (b,p,c) bf16 [+ optional xbc bf16 (b,c,p)] ----------------
__global__ __launch_bounds__(256) void k_xt(const float* __restrict__ x, ushort* __restrict__ xt,
                                            ushort* __restrict__ xbc, int use_xbc) {
    __shared__ float tile[64][65];
    int p0 = blockIdx.x * 64, c0 = blockIdx.y * 64, bat = blockIdx.z;
    int tx = threadIdx.x, ty = threadIdx.y;            // (32,8)
    const float* xb = x + ((size_t)bat * C_ + c0) * P_ + p0;
    #pragma unroll
    for (int i = ty; i < 64; i += 8) {
        float2 v = *(const float2*)&xb[(size_t)i * P_ + 2 * tx];
        tile[i][2 * tx] = v.x; tile[i][2 * tx + 1] = v.y;
        if (use_xbc) {
            ushort2 bv; bv.x = f2bf(v.x); bv.y = f2bf(v.y);
            *(ushort2*)&xbc[((size_t)bat * C_ + c0 + i) * P_ + p0 + 2 * tx] = bv;
        }
    }
    __syncthreads();
    ushort* o = xt + ((size_t)bat * P_ + p0) * C_ + c0;
    #pragma unroll
    for (int i = ty; i < 64; i += 8) {
        ushort2 v; v.x = f2bf(tile[2 * tx][i]); v.y = f2bf(tile[2 * tx + 1][i]);
        *(ushort2*)&o[(size_t)i * C_ + 2 * tx] = v;
    }
}

// ---------------- K0b: weights -> bf16 combined [640][512]; ball[640] ----------------
__global__ __launch_bounds__(256) void k_wconv(const float* __restrict__ Wq, const float* __restrict__ Wk,
                                               const float* __restrict__ Wv, const float* __restrict__ bq,
                                               const float* __restrict__ bk, const float* __restrict__ bv,
                                               ushort* __restrict__ Wall, float* __restrict__ ball) {
    int idx = blockIdx.x * 256 + threadIdx.x;
    if (idx < 640) {
        float b;
        if (idx < 64)       b = bq[idx];
        else if (idx < 128) b = bk[idx - 64];
        else                b = bv[idx - 128];
        ball[idx] = b;
    }
    if (idx >= 640 * C_) return;
    int o = idx / C_, c = idx % C_;
    float v;
    if (o < 64)       v = Wq[o * C_ + c];
    else if (o < 128) v = Wk[(o - 64) * C_ + c];
    else              v = Wv[(o - 128) * C_ + c];
    Wall[idx] = f2bf(v);
}

// ---------------- K1: projection GEMM (m97 structure). M=640(o) x N=NP(pix), K=512 ----------------
// tile 128x128, BK=32, 4 waves (2x2 of 64x64), global_load_lds staging, XCD-chunk swizzle.
__global__ __launch_bounds__(256, 4) void k_proj(const ushort* __restrict__ xt, const ushort* __restrict__ Wall,
                                                 const float* __restrict__ ball,
                                                 ushort* __restrict__ Qcm, ushort* __restrict__ Kcm,
                                                 ushort* __restrict__ Vcm) {
    __shared__ __align__(16) ushort Al[128 * 32];     // [o][k] 8KB
    __shared__ __align__(16) ushort Bl[128 * 32];     // [pix][k] 8KB
    int tid = threadIdx.x, lane = tid & 63, wv = tid >> 6;
    int wr = wv >> 1, wc = wv & 1;
    // bijective XCD swizzle: 2880 blocks, 8 XCDs, 360/XCD; m fastest within XCD chunk
    int wg = ((int)blockIdx.x & 7) * 360 + ((int)blockIdx.x >> 3);
    int m0 = (wg % 5) * 128;
    int n0 = (wg / 5) * 128;
    f32x4 acc[4][4] = {};
    for (int kb = 0; kb < C_; kb += 32) {
        #pragma unroll
        for (int i = 0; i < 2; ++i) {
            int u = tid + i * 256, row = u >> 2, seg = u & 3;
            GLL16(&Wall[(size_t)(m0 + row) * C_ + kb + seg * 8], &Al[(size_t)u * 8]);
            GLL16(&xt[(size_t)(n0 + row) * C_ + kb + seg * 8],   &Bl[(size_t)u * 8]);
        }
        __syncthreads();
        int rr = lane & 15, gq = lane >> 4;
        short8 fb[4];
        #pragma unroll
        for (int nt = 0; nt < 4; ++nt) fb[nt] = *(const short8*)&Bl[(wc * 64 + nt * 16 + rr) * 32 + gq * 8];
        #pragma unroll
        for (int mt = 0; mt < 4; ++mt) {
            short8 fa = *(const short8*)&Al[(wr * 64 + mt * 16 + rr) * 32 + gq * 8];
            #pragma unroll
            for (int nt = 0; nt < 4; ++nt)
                acc[mt][nt] = __builtin_amdgcn_mfma_f32_16x16x32_bf16(fa, fb[nt], acc[mt][nt], 0, 0, 0);
        }
        __syncthreads();
    }
    int rr = lane & 15, gq = lane >> 4;
    int bat = n0 / P_, pb0 = n0 - bat * P_;
    #pragma unroll
    for (int mt = 0; mt < 4; ++mt)
        #pragma unroll
        for (int nt = 0; nt < 4; ++nt) {
            int col = wc * 64 + nt * 16 + rr;
            #pragma unroll
            for (int q = 0; q < 4; ++q) {
                int o = m0 + wr * 64 + mt * 16 + gq * 4 + q;
                float v = acc[mt][nt][q] + ball[o];
                if (o < 64)       Qcm[(size_t)o * NP + n0 + col] = f2bf(v);
                else if (o < 128) Kcm[(size_t)(o - 64) * NP + n0 + col] = f2bf(v);
                else              Vcm[((size_t)bat * C_ + (o - 128)) * P_ + pb0 + col] = f2bf(v);
            }
        }
}

// ---------------- K1b: Qcm/Kcm [64][NP] -> Qb/Kb [NP][64] ----------------
__global__ __launch_bounds__(256) void k_qkt(const ushort* __restrict__ Qcm, const ushort* __restrict__ Kcm,
                                             ushort* __restrict__ Qb, ushort* __restrict__ Kb) {
    __shared__ ushort t[64][65];
    int p0 = blockIdx.x * 64;
    const ushort* src = blockIdx.y ? Kcm : Qcm;
    ushort* dst = blockIdx.y ? Kb : Qb;
    int tx = threadIdx.x, ty = threadIdx.y;            // (64,4)
    #pragma unroll
    for (int i = ty; i < 64; i += 4) t[i][tx] = src[(size_t)i * NP + p0 + tx];
    __syncthreads();
    #pragma unroll
    for (int i = ty; i < 64; i += 4) dst[(size_t)(p0 + i) * CQ_ + tx] = t[tx][i];
}

// ---------------- K3: Vcm (b,c,h,w) -> Vt (b,w,c,h); one plane per block ----------------
__global__ __launch_bounds__(256) void k_vt(const ushort* __restrict__ Vcm, ushort* __restrict__ Vt) {
    __shared__ ushort t[96 * 98];
    int c = blockIdx.x, bat = blockIdx.y;
    const ushort* src = Vcm + ((size_t)(bat * C_ + c)) * P_;
    int tid = threadIdx.x;
    for (int u = tid; u < 2304; u += 256) {            // 96 rows x 24 ushort4
        int h = u / 24, w4 = (u % 24) * 4;
        us4 v = *(const us4*)&src[h * 96 + w4];
        ushort2 a; a.x = v.x; a.y = v.y;
        ushort2 b; b.x = v.z; b.y = v.w;
        *(ushort2*)&t[h * 98 + w4]     = a;
        *(ushort2*)&t[h * 98 + w4 + 2] = b;
    }
    __syncthreads();
    for (int u = tid; u < 2304; u += 256) {            // 96 w-rows x 24 ushort4 (h)
        int w = u / 24, h4 = (u % 24) * 4;
        us4 o;
        o.x = t[(h4 + 0) * 98 + w];
        o.y = t[(h4 + 1) * 98 + w];
        o.z = t[(h4 + 2) * 98 + w];
        o.w = t[(h4 + 3) * 98 + w];
        *(us4*)&Vt[((size_t)(bat * W_ + w) * C_ + c) * H_ + h4] = o;
    }
}

// ---------------- K4: e_row. block (h,b): M=96(w) N=96(v) K=64 ----------------
#define LSTR 40
__global__ __launch_bounds__(256) void k_erow(const ushort* __restrict__ Qb, const ushort* __restrict__ Kb,
                                              float* __restrict__ logits) {
    __shared__ __align__(16) ushort Al[96 * LSTR];
    __shared__ __align__(16) ushort Bl[96 * LSTR];
    int h = blockIdx.x, bat = blockIdx.y;
    int tid = threadIdx.x, lane = tid & 63, wvid = tid >> 6;
    int wr = wvid >> 1, wc = wvid & 1;                 // wave tile 48x48
    size_t base = ((size_t)bat * H_ + h) * W_;
    f32x4 acc[3][3] = {};
    for (int kb = 0; kb < CQ_; kb += 32) {
        for (int s = tid; s < 96 * 4; s += 256) {
            int row = s >> 2, seg = s & 3;
            *(short8*)&Al[row * LSTR + seg * 8] = *(const short8*)&Qb[(base + row) * CQ_ + kb + seg * 8];
            *(short8*)&Bl[row * LSTR + seg * 8] = *(const short8*)&Kb[(base + row) * CQ_ + kb + seg * 8];
        }
        __syncthreads();
        int rr = lane & 15, gq = lane >> 4;
        #pragma unroll
        for (int mt = 0; mt < 3; ++mt) {
            short8 fa = *(const short8*)&Al[(wr * 48 + mt * 16 + rr) * LSTR + gq * 8];
            #pragma unroll
            for (int nt = 0; nt < 3; ++nt) {
                short8 fb = *(const short8*)&Bl[(wc * 48 + nt * 16 + rr) * LSTR + gq * 8];
                acc[mt][nt] = __builtin_amdgcn_mfma_f32_16x16x32_bf16(fa, fb, acc[mt][nt], 0, 0, 0);
            }
        }
        __syncthreads();
    }
    int rr = lane & 15, gq = lane >> 4;
    #pragma unroll
    for (int mt = 0; mt < 3; ++mt)
        #pragma unroll
        for (int nt = 0; nt < 3; ++nt)
            #pragma unroll
            for (int q = 0; q < 4; ++q) {
                int w = wr * 48 + mt * 16 + gq * 4 + q;
                int v = wc * 48 + nt * 16 + rr;
                logits[(base + w) * L_ + v] = acc[mt][nt][q];
            }
}

// ---------------- K5: e_col. block (w,b): M=96(h) N=96(g) K=64 ----------------
__global__ __launch_bounds__(256) void k_ecol(const ushort* __restrict__ Qb, const ushort* __restrict__ Kb,
                                              float* __restrict__ logits) {
    __shared__ __align__(16) ushort Al[96 * LSTR];
    __shared__ __align__(16) ushort Bl[96 * LSTR];
    int w = blockIdx.x, bat = blockIdx.y;
    int tid = threadIdx.x, lane = tid & 63, wvid = tid >> 6;
    int wr = wvid >> 1, wc = wvid & 1;
    f32x4 acc[3][3] = {};
    for (int kb = 0; kb < CQ_; kb += 32) {
        for (int s = tid; s < 96 * 4; s += 256) {
            int row = s >> 2, seg = s & 3;
            size_t px = ((size_t)bat * H_ + row) * W_ + w;
            *(short8*)&Al[row * LSTR + seg * 8] = *(const short8*)&Qb[px * CQ_ + kb + seg * 8];
            *(short8*)&Bl[row * LSTR + seg * 8] = *(const short8*)&Kb[px * CQ_ + kb + seg * 8];
        }
        __syncthreads();
        int rr = lane & 15, gq = lane >> 4;
        #pragma unroll
        for (int mt = 0; mt < 3; ++mt) {
            short8 fa = *(const short8*)&Al[(wr * 48 + mt * 16 + rr) * LSTR + gq * 8];
            #pragma unroll
            for (int nt = 0; nt < 3; ++nt) {
                short8 fb = *(const short8*)&Bl[(wc * 48 + nt * 16 + rr) * LSTR + gq * 8];
                acc[mt][nt] = __builtin_amdgcn_mfma_f32_16x16x32_bf16(fa, fb, acc[mt][nt], 0, 0, 0);
            }
        }
        __syncthreads();
    }
    int rr = lane & 15, gq = lane >> 4;
    #pragma unroll
    for (int mt = 0; mt < 3; ++mt)
        #pragma unroll
        for (int nt = 0; nt < 3; ++nt)
            #pragma unroll
            for (int q = 0; q < 4; ++q) {
                int hh = wr * 48 + mt * 16 + gq * 4 + q;
                int gg = wc * 48 + nt * 16 + rr;
                logits[(((size_t)bat * H_ + hh) * W_ + w) * L_ + W_ + gg] = acc[mt][nt][q];
            }
}

// ---------------- K6: softmax over 192, one wave per pixel ----------------
__global__ __launch_bounds__(256) void k_softmax(const float* __restrict__ logits, ushort* __restrict__ attn) {
    int wvid = threadIdx.x >> 6, lane = threadIdx.x & 63;
    size_t px = (size_t)blockIdx.x * 4 + wvid;
    const float* lp = logits + px * L_;
    float v0 = lp[lane], v1 = lp[lane + 64], v2 = lp[lane + 128];
    float m = fmaxf(fmaxf(v0, v1), v2);
    #pragma unroll
    for (int off = 32; off; off >>= 1) m = fmaxf(m, __shfl_xor(m, off));
    float e0 = __expf(v0 - m), e1 = __expf(v1 - m), e2 = __expf(v2 - m);
    float s = e0 + e1 + e2;
    #pragma unroll
    for (int off = 32; off; off >>= 1) s += __shfl_xor(s, off);
    float inv = 1.0f / s;
    ushort* ap = attn + px * L_;
    ap[lane] = f2bf(e0 * inv); ap[lane + 64] = f2bf(e1 * inv); ap[lane + 128] = f2bf(e2 * inv);
}

// ---------------- K7: row PV. block (h,b): M=512(c) N=96(w) K=96(v) ----------------
__global__ __launch_bounds__(512, 4) void k_pvrow(const ushort* __restrict__ Vcm, const ushort* __restrict__ attn,
                                                  ushort* __restrict__ out0) {
    __shared__ __align__(16) ushort Al[512 * 32];     // [c][v] 32KB
    __shared__ __align__(16) ushort Bl[96 * 32];      // [w][v] 6KB
    int h = blockIdx.x, bat = blockIdx.y;
    int tid = threadIdx.x, lane = tid & 63, wvid = tid >> 6;
    int wrm = wvid >> 1, wcn = wvid & 1;              // 4m x 2n, wave tile 128x48
    size_t vbase = (size_t)bat * C_ * P_ + (size_t)h * W_;
    size_t abase = ((size_t)bat * H_ + h) * W_ * L_;
    f32x4 acc[8][3] = {};
    for (int kb = 0; kb < 96; kb += 32) {
        #pragma unroll
        for (int i = 0; i < 4; ++i) {                 // A: 512 rows x 64B
            int u = tid + i * 512, row = u >> 2, seg = u & 3;
            GLL16(&Vcm[vbase + (size_t)row * P_ + kb + seg * 8], &Al[(size_t)u * 8]);
        }
        if (tid < 384) {                              // B: 96 rows x 64B (waves 0-5)
            int row = tid >> 2, seg = tid & 3;
            GLL16(&attn[abase + (size_t)row * L_ + kb + seg * 8], &Bl[(size_t)tid * 8]);
        }
        __syncthreads();
        int rr = lane & 15, gq = lane >> 4;
        short8 fb[3];
        #pragma unroll
        for (int nt = 0; nt < 3; ++nt) fb[nt] = *(const short8*)&Bl[(wcn * 48 + nt * 16 + rr) * 32 + gq * 8];
        #pragma unroll
        for (int mt = 0; mt < 8; ++mt) {
            short8 fa = *(const short8*)&Al[(wrm * 128 + mt * 16 + rr) * 32 + gq * 8];
            #pragma unroll
            for (int nt = 0; nt < 3; ++nt)
                acc[mt][nt] = __builtin_amdgcn_mfma_f32_16x16x32_bf16(fa, fb[nt], acc[mt][nt], 0, 0, 0);
        }
        __syncthreads();
    }
    int rr = lane & 15, gq = lane >> 4;
    #pragma unroll
    for (int mt = 0; mt < 8; ++mt)
        #pragma unroll
        for (int nt = 0; nt < 3; ++nt) {
            int w = wcn * 48 + nt * 16 + rr;
            #pragma unroll
            for (int q = 0; q < 4; ++q) {
                int c = wrm * 128 + mt * 16 + gq * 4 + q;
                out0[((size_t)bat * C_ + c) * P_ + (size_t)h * W_ + w] = f2bf(acc[mt][nt][q]);
            }
        }
}

// ---------------- K8: col PV. block (w,b): M=512(c) N=96(h) K=96(g); out (b,c,w,h) ----------------
__global__ __launch_bounds__(512, 4) void k_pvcol(const ushort* __restrict__ Vt, const ushort* __restrict__ attn,
                                                  ushort* __restrict__ out1t) {
    __shared__ __align__(16) ushort Al[512 * 32];     // [c][g]
    __shared__ __align__(16) ushort Bl[96 * 32];      // [h][g]
    int w = blockIdx.x, bat = blockIdx.y;
    int tid = threadIdx.x, lane = tid & 63, wvid = tid >> 6;
    int wrm = wvid >> 1, wcn = wvid & 1;
    size_t vbase = ((size_t)bat * W_ + w) * C_ * H_;
    size_t abase = ((size_t)bat * P_ + w) * L_ + W_;
    f32x4 acc[8][3] = {};
    for (int kb = 0; kb < 96; kb += 32) {
        #pragma unroll
        for (int i = 0; i < 4; ++i) {
            int u = tid + i * 512, row = u >> 2, seg = u & 3;
            GLL16(&Vt[vbase + (size_t)row * H_ + kb + seg * 8], &Al[(size_t)u * 8]);
        }
        if (tid < 384) {
            int row = tid >> 2, seg = tid & 3;
            GLL16(&attn[abase + (size_t)row * (W_ * L_) + kb + seg * 8], &Bl[(size_t)tid * 8]);
        }
        __syncthreads();
        int rr = lane & 15, gq = lane >> 4;
        short8 fb[3];
        #pragma unroll
        for (int nt = 0; nt < 3; ++nt) fb[nt] = *(const short8*)&Bl[(wcn * 48 + nt * 16 + rr) * 32 + gq * 8];
        #pragma unroll
        for (int mt = 0; mt < 8; ++mt) {
            short8 fa = *(const short8*)&Al[(wrm * 128 + mt * 16 + rr) * 32 + gq * 8];
            #pragma unroll
            for (int nt = 0; nt < 3; ++nt)
                acc[mt][nt] = __builtin_amdgcn_mfma_f32_16x16x32_bf16(fa, fb[nt], acc[mt][nt], 0, 0, 0);
        }
        __syncthreads();
    }
    int rr = lane & 15, gq = lane >> 4;
    #pragma unroll
    for (int mt = 0; mt < 8; ++mt)
        #pragma unroll
        for (int nt = 0; nt < 3; ++nt) {
            int hh = wcn * 48 + nt * 16 + rr;
            #pragma unroll
            for (int q = 0; q < 4; ++q) {
                int c = wrm * 128 + mt * 16 + gq * 4 + q;
                out1t[((size_t)(bat * C_ + c) * W_ + w) * H_ + hh] = f2bf(acc[mt][nt][q]);
            }
        }
}

// ---------------- K9: per-(b,c) plane: out = x + gamma*(out0 + out1t^T) ----------------
__global__ __launch_bounds__(256) void k_final(const float* __restrict__ x, const ushort* __restrict__ xbc,
                                               const ushort* __restrict__ out0, const ushort* __restrict__ out1t,
                                               const float* __restrict__ gamma, float* __restrict__ out,
                                               int use_xbc) {
    __shared__ ushort t[96 * 98];
    int c = blockIdx.x, bat = blockIdx.y;
    const ushort* src = out1t + ((size_t)bat * C_ + c) * P_;   // plane [w][h]
    int tid = threadIdx.x;
    for (int i = tid; i < 4608; i += 256) {
        int w = i / 48, h = (i % 48) * 2;
        ushort2 v = *(const ushort2*)&src[w * 96 + h];
        *(ushort2*)&t[w * 98 + h] = v;
    }
    __syncthreads();
    float gm = gamma[0];
    size_t base = ((size_t)bat * C_ + c) * P_;
    for (int i = tid; i < 4608; i += 256) {
        int h = i / 48, w = (i % 48) * 2;
        size_t idx = base + h * W_ + w;
        float xa, xbv;
        if (use_xbc) {
            ushort2 xv = *(const ushort2*)&xbc[idx];
            xa = bf2f(xv.x); xbv = bf2f(xv.y);
        } else {
            float2 xv = *(const float2*)&x[idx];
            xa = xv.x; xbv = xv.y;
        }
        ushort2 o0 = *(const ushort2*)&out0[idx];
        float2 r;
        r.x = xa  + gm * (bf2f(o0.x) + bf2f(t[w * 98 + h]));
        r.y = xbv + gm * (bf2f(o0.y) + bf2f(t[(w + 1) * 98 + h]));
        *(float2*)&out[idx] = r;
    }
}

extern "C" void kernel_launch(void* const* d_in, const int* in_sizes, int n_in,
                              void* d_out, int out_size, void* d_ws, size_t ws_size,
                              hipStream_t stream) {
    const float* x     = (const float*)d_in[0];
    const float* Wq    = (const float*)d_in[1];
    const float* bq    = (const float*)d_in[2];
    const float* Wk    = (const float*)d_in[3];
    const float* bk    = (const float*)d_in[4];
    const float* Wv    = (const float*)d_in[5];
    const float* bv    = (const float*)d_in[6];
    const float* gamma = (const float*)d_in[7];
    float* out = (float*)d_out;
    char* ws = (char*)d_ws;

    const size_t SZ  = (size_t)NP * C_ * 2;           // 75,497,472 B
    const size_t QKS = (size_t)NP * CQ_ * 2;          // 9,437,184 B
    // Region A: Qcm | Kcm | logits  -> later reused as out1t
    ushort* Qcm    = (ushort*)(ws);
    ushort* Kcm    = (ushort*)(ws + QKS);
    float*  logits = (float*) (ws + 2 * QKS);
    ushort* out1t  = (ushort*)(ws);
    // Region B: xt -> later out0
    ushort* xt     = (ushort*)(ws + SZ);
    ushort* out0   = xt;
    // Region C, D
    ushort* Vcm    = (ushort*)(ws + 2 * SZ);
    ushort* Vt     = (ushort*)(ws + 3 * SZ);
    // Region E: Qb|Kb (dead after ecol) -> attn overwrites
    ushort* Qb     = (ushort*)(ws + 4 * SZ);
    ushort* Kb     = (ushort*)(ws + 4 * SZ + QKS);
    ushort* attn   = (ushort*)(ws + 4 * SZ);
    // Region W
    size_t off_wall = 4 * SZ + (size_t)NP * L_ * 2;
    ushort* Wall   = (ushort*)(ws + off_wall);
    float*  ball   = (float*) (ws + off_wall + 640 * C_ * 2);
    size_t off_xbc = off_wall + 640 * C_ * 2 + 4096;
    ushort* xbc    = (ushort*)(ws + off_xbc);
    int use_xbc = (ws_size >= off_xbc + SZ) ? 1 : 0;

    k_xt     <<<dim3(144, 8, 8),  dim3(32, 8), 0, stream>>>(x, xt, xbc, use_xbc);
    k_wconv  <<<dim3(1280),       dim3(256),   0, stream>>>(Wq, Wk, Wv, bq, bk, bv, Wall, ball);
    k_proj   <<<dim3(2880),       dim3(256),   0, stream>>>(xt, Wall, ball, Qcm, Kcm, Vcm);
    k_qkt    <<<dim3(1152, 2),    dim3(64, 4), 0, stream>>>(Qcm, Kcm, Qb, Kb);
    k_vt     <<<dim3(512, 8),     dim3(256),   0, stream>>>(Vcm, Vt);
    k_erow   <<<dim3(96, 8),      dim3(256),   0, stream>>>(Qb, Kb, logits);
    k_ecol   <<<dim3(96, 8),      dim3(256),   0, stream>>>(Qb, Kb, logits);
    k_softmax<<<dim3(NP / 4),     dim3(256),   0, stream>>>(logits, attn);
    k_pvrow  <<<dim3(96, 8),      dim3(512),   0, stream>>>(Vcm, attn, out0);
    k_pvcol  <<<dim3(96, 8),      dim3(512),   0, stream>>>(Vt, attn, out1t);
    k_final  <<<dim3(512, 8),     dim3(256),   0, stream>>>(x, xbc, out0, out1t, gamma, out, use_xbc);
}

// Round 4
// 399.173 us; speedup vs baseline: 1.1552x; 1.1552x over previous
//
#include <hip/hip_runtime.h>
#include <stdint.h>

#define B_  8
#define C_  512
#define H_  96
#define W_  96
#define CQ_ 64
#define P_  (H_*W_)     // 9216 pixels per batch
#define NP  (B_*P_)     // 73728
#define L_  (W_+H_)     // 192 logits per pixel

typedef __attribute__((ext_vector_type(8))) short short8;
typedef __attribute__((ext_vector_type(4))) float f32x4;
typedef __attribute__((ext_vector_type(4))) unsigned short us4;

__device__ __forceinline__ ushort f2bf(float f) {
    uint32_t u = __builtin_bit_cast(uint32_t, f);
    u += 0x7fff + ((u >> 16) & 1);
    return (ushort)(u >> 16);
}
__device__ __forceinline__ float bf2f(ushort h) {
    uint32_t u = ((uint32_t)h) << 16;
    return __builtin_bit_cast(float, u);
}

// global -> LDS direct 16B copy (dest must be uniform-base + lane*16 pattern)
#define GLL16(g, l) __builtin_amdgcn_global_load_lds( \
    (const __attribute__((address_space(1))) uint32_t*)(g), \
    (__attribute__((address_space(3))) uint32_t*)(l), 16, 0, 0)

// ---------------- K0b: weights -> bf16 combined [640][512]; ball[640] ----------------
__global__ __launch_bounds__(256) void k_wconv(const float* __restrict__ Wq, const float* __restrict__ Wk,
                                               const float* __restrict__ Wv, const float* __restrict__ bq,
                                               const float* __restrict__ bk, const float* __restrict__ bv,
                                               ushort* __restrict__ Wall, float* __restrict__ ball) {
    int idx = blockIdx.x * 256 + threadIdx.x;
    if (idx < 640) {
        float b;
        if (idx < 64)       b = bq[idx];
        else if (idx < 128) b = bk[idx - 64];
        else                b = bv[idx - 128];
        ball[idx] = b;
    }
    if (idx >= 640 * C_) return;
    int o = idx / C_, c = idx % C_;
    float v;
    if (o < 64)       v = Wq[o * C_ + c];
    else if (o < 128) v = Wk[(o - 64) * C_ + c];
    else              v = Wv[(o - 128) * C_ + c];
    Wall[idx] = f2bf(v);
}

// ---------------- K1: fused projection GEMM, reads x fp32 directly ----------------
// M=640(o) x N=NP(pix), K=512. tile 128x128, BK=32, 4 waves.
// B-operand: x[c][p] tile loaded fp32-coalesced, converted, LDS-transposed to [p][c] (LSTR 40).
// m0==0 blocks also emit xbc (bf16 copy of x, channel-major) for k_final.
#define LSTR 40
__global__ __launch_bounds__(256, 4) void k_proj(const float* __restrict__ x, const ushort* __restrict__ Wall,
                                                 const float* __restrict__ ball,
                                                 ushort* __restrict__ Qcm, ushort* __restrict__ Kcm,
                                                 ushort* __restrict__ Vcm, ushort* __restrict__ xbc) {
    __shared__ __align__(16) ushort Al[128 * 32];     // [o][k] 8KB, linear for GLL
    __shared__ __align__(16) ushort Bl[128 * LSTR];   // [pix][k] 10KB, padded
    int tid = threadIdx.x, lane = tid & 63, wv = tid >> 6;
    int wr = wv >> 1, wc = wv & 1;
    // bijective XCD swizzle: 2880 blocks = 8 XCDs x 360; m fastest within chunk
    int wg = ((int)blockIdx.x & 7) * 360 + ((int)blockIdx.x >> 3);
    int m0 = (wg % 5) * 128;
    int n0 = (wg / 5) * 128;
    int bat = n0 / P_, pb0 = n0 - bat * P_;
    // B-staging geometry: p_loc = lane + (wv&1)*64 (0..127), chalf = wv>>1 (0..1)
    int p_loc = lane + (wv & 1) * 64;
    int chalf = (wv >> 1) & 1;                         // wv 0..3 -> chalf 0,0,1,1
    const float* xp = x + ((size_t)bat * C_) * P_ + pb0 + p_loc;
    ushort* xbp = xbc + ((size_t)bat * C_) * P_ + pb0 + p_loc;
    int do_xbc = (m0 == 0);
    f32x4 acc[4][4] = {};
    for (int kb = 0; kb < C_; kb += 32) {
        // A: 128 rows x 64B via global_load_lds
        #pragma unroll
        for (int i = 0; i < 2; ++i) {
            int u = tid + i * 256, row = u >> 2, seg = u & 3;
            GLL16(&Wall[(size_t)(m0 + row) * C_ + kb + seg * 8], &Al[(size_t)u * 8]);
        }
        // B: 32c x 128p fp32 -> bf16 -> LDS [p][c]
        #pragma unroll
        for (int g = 0; g < 2; ++g) {
            int c0 = chalf * 16 + g * 8;               // k-offset within step
            ushort u8[8];
            #pragma unroll
            for (int j = 0; j < 8; ++j)
                u8[j] = f2bf(xp[(size_t)(kb + c0 + j) * P_]);
            if (do_xbc) {
                #pragma unroll
                for (int j = 0; j < 8; ++j)
                    xbp[(size_t)(kb + c0 + j) * P_] = u8[j];
            }
            short8 pk;
            #pragma unroll
            for (int j = 0; j < 8; ++j) pk[j] = (short)u8[j];
            *(short8*)&Bl[p_loc * LSTR + c0] = pk;
        }
        __syncthreads();
        int rr = lane & 15, gq = lane >> 4;
        short8 fb[4];
        #pragma unroll
        for (int nt = 0; nt < 4; ++nt) fb[nt] = *(const short8*)&Bl[(wc * 64 + nt * 16 + rr) * LSTR + gq * 8];
        #pragma unroll
        for (int mt = 0; mt < 4; ++mt) {
            short8 fa = *(const short8*)&Al[(wr * 64 + mt * 16 + rr) * 32 + gq * 8];
            #pragma unroll
            for (int nt = 0; nt < 4; ++nt)
                acc[mt][nt] = __builtin_amdgcn_mfma_f32_16x16x32_bf16(fa, fb[nt], acc[mt][nt], 0, 0, 0);
        }
        __syncthreads();
    }
    int rr = lane & 15, gq = lane >> 4;
    #pragma unroll
    for (int mt = 0; mt < 4; ++mt)
        #pragma unroll
        for (int nt = 0; nt < 4; ++nt) {
            int col = wc * 64 + nt * 16 + rr;
            #pragma unroll
            for (int q = 0; q < 4; ++q) {
                int o = m0 + wr * 64 + mt * 16 + gq * 4 + q;
                float v = acc[mt][nt][q] + ball[o];
                if (o < 64)       Qcm[(size_t)o * NP + n0 + col] = f2bf(v);
                else if (o < 128) Kcm[(size_t)(o - 64) * NP + n0 + col] = f2bf(v);
                else              Vcm[((size_t)bat * C_ + (o - 128)) * P_ + pb0 + col] = f2bf(v);
            }
        }
}

// ---------------- K1b: Qcm/Kcm [64][NP] -> Qb/Kb [NP][64] ----------------
__global__ __launch_bounds__(256) void k_qkt(const ushort* __restrict__ Qcm, const ushort* __restrict__ Kcm,
                                             ushort* __restrict__ Qb, ushort* __restrict__ Kb) {
    __shared__ ushort t[64][65];
    int p0 = blockIdx.x * 64;
    const ushort* src = blockIdx.y ? Kcm : Qcm;
    ushort* dst = blockIdx.y ? Kb : Qb;
    int tx = threadIdx.x, ty = threadIdx.y;            // (64,4)
    #pragma unroll
    for (int i = ty; i < 64; i += 4) t[i][tx] = src[(size_t)i * NP + p0 + tx];
    __syncthreads();
    #pragma unroll
    for (int i = ty; i < 64; i += 4) dst[(size_t)(p0 + i) * CQ_ + tx] = t[tx][i];
}

// ---------------- K3: Vcm (b,c,h,w) -> Vt (b,w,c,h); one plane per block ----------------
__global__ __launch_bounds__(256) void k_vt(const ushort* __restrict__ Vcm, ushort* __restrict__ Vt) {
    __shared__ ushort t[96 * 98];
    int c = blockIdx.x, bat = blockIdx.y;
    const ushort* src = Vcm + ((size_t)(bat * C_ + c)) * P_;
    int tid = threadIdx.x;
    for (int u = tid; u < 2304; u += 256) {            // 96 rows x 24 ushort4
        int h = u / 24, w4 = (u % 24) * 4;
        us4 v = *(const us4*)&src[h * 96 + w4];
        ushort2 a; a.x = v.x; a.y = v.y;
        ushort2 b; b.x = v.z; b.y = v.w;
        *(ushort2*)&t[h * 98 + w4]     = a;
        *(ushort2*)&t[h * 98 + w4 + 2] = b;
    }
    __syncthreads();
    for (int u = tid; u < 2304; u += 256) {            // 96 w-rows x 24 ushort4 (h)
        int w = u / 24, h4 = (u % 24) * 4;
        us4 o;
        o.x = t[(h4 + 0) * 98 + w];
        o.y = t[(h4 + 1) * 98 + w];
        o.z = t[(h4 + 2) * 98 + w];
        o.w = t[(h4 + 3) * 98 + w];
        *(us4*)&Vt[((size_t)(bat * W_ + w) * C_ + c) * H_ + h4] = o;
    }
}

// ---------------- K4: e_row. block (h,b): M=96(w) N=96(v) K=64 ----------------
__global__ __launch_bounds__(256) void k_erow(const ushort* __restrict__ Qb, const ushort* __restrict__ Kb,
                                              float* __restrict__ logits) {
    __shared__ __align__(16) ushort Al[96 * LSTR];
    __shared__ __align__(16) ushort Bl[96 * LSTR];
    int h = blockIdx.x, bat = blockIdx.y;
    int tid = threadIdx.x, lane = tid & 63, wvid = tid >> 6;
    int wr = wvid >> 1, wc = wvid & 1;                 // wave tile 48x48
    size_t base = ((size_t)bat * H_ + h) * W_;
    f32x4 acc[3][3] = {};
    for (int kb = 0; kb < CQ_; kb += 32) {
        for (int s = tid; s < 96 * 4; s += 256) {
            int row = s >> 2, seg = s & 3;
            *(short8*)&Al[row * LSTR + seg * 8] = *(const short8*)&Qb[(base + row) * CQ_ + kb + seg * 8];
            *(short8*)&Bl[row * LSTR + seg * 8] = *(const short8*)&Kb[(base + row) * CQ_ + kb + seg * 8];
        }
        __syncthreads();
        int rr = lane & 15, gq = lane >> 4;
        #pragma unroll
        for (int mt = 0; mt < 3; ++mt) {
            short8 fa = *(const short8*)&Al[(wr * 48 + mt * 16 + rr) * LSTR + gq * 8];
            #pragma unroll
            for (int nt = 0; nt < 3; ++nt) {
                short8 fb = *(const short8*)&Bl[(wc * 48 + nt * 16 + rr) * LSTR + gq * 8];
                acc[mt][nt] = __builtin_amdgcn_mfma_f32_16x16x32_bf16(fa, fb, acc[mt][nt], 0, 0, 0);
            }
        }
        __syncthreads();
    }
    int rr = lane & 15, gq = lane >> 4;
    #pragma unroll
    for (int mt = 0; mt < 3; ++mt)
        #pragma unroll
        for (int nt = 0; nt < 3; ++nt)
            #pragma unroll
            for (int q = 0; q < 4; ++q) {
                int w = wr * 48 + mt * 16 + gq * 4 + q;
                int v = wc * 48 + nt * 16 + rr;
                logits[(base + w) * L_ + v] = acc[mt][nt][q];
            }
}

// ---------------- K5: e_col. block (w,b): M=96(h) N=96(g) K=64 ----------------
__global__ __launch_bounds__(256) void k_ecol(const ushort* __restrict__ Qb, const ushort* __restrict__ Kb,
                                              float* __restrict__ logits) {
    __shared__ __align__(16) ushort Al[96 * LSTR];
    __shared__ __align__(16) ushort Bl[96 * LSTR];
    int w = blockIdx.x, bat = blockIdx.y;
    int tid = threadIdx.x, lane = tid & 63, wvid = tid >> 6;
    int wr = wvid >> 1, wc = wvid & 1;
    f32x4 acc[3][3] = {};
    for (int kb = 0; kb < CQ_; kb += 32) {
        for (int s = tid; s < 96 * 4; s += 256) {
            int row = s >> 2, seg = s & 3;
            size_t px = ((size_t)bat * H_ + row) * W_ + w;
            *(short8*)&Al[row * LSTR + seg * 8] = *(const short8*)&Qb[px * CQ_ + kb + seg * 8];
            *(short8*)&Bl[row * LSTR + seg * 8] = *(const short8*)&Kb[px * CQ_ + kb + seg * 8];
        }
        __syncthreads();
        int rr = lane & 15, gq = lane >> 4;
        #pragma unroll
        for (int mt = 0; mt < 3; ++mt) {
            short8 fa = *(const short8*)&Al[(wr * 48 + mt * 16 + rr) * LSTR + gq * 8];
            #pragma unroll
            for (int nt = 0; nt < 3; ++nt) {
                short8 fb = *(const short8*)&Bl[(wc * 48 + nt * 16 + rr) * LSTR + gq * 8];
                acc[mt][nt] = __builtin_amdgcn_mfma_f32_16x16x32_bf16(fa, fb, acc[mt][nt], 0, 0, 0);
            }
        }
        __syncthreads();
    }
    int rr = lane & 15, gq = lane >> 4;
    #pragma unroll
    for (int mt = 0; mt < 3; ++mt)
        #pragma unroll
        for (int nt = 0; nt < 3; ++nt)
            #pragma unroll
            for (int q = 0; q < 4; ++q) {
                int hh = wr * 48 + mt * 16 + gq * 4 + q;
                int gg = wc * 48 + nt * 16 + rr;
                logits[(((size_t)bat * H_ + hh) * W_ + w) * L_ + W_ + gg] = acc[mt][nt][q];
            }
}

// ---------------- K6: softmax over 192, one wave per pixel ----------------
__global__ __launch_bounds__(256) void k_softmax(const float* __restrict__ logits, ushort* __restrict__ attn) {
    int wvid = threadIdx.x >> 6, lane = threadIdx.x & 63;
    size_t px = (size_t)blockIdx.x * 4 + wvid;
    const float* lp = logits + px * L_;
    float v0 = lp[lane], v1 = lp[lane + 64], v2 = lp[lane + 128];
    float m = fmaxf(fmaxf(v0, v1), v2);
    #pragma unroll
    for (int off = 32; off; off >>= 1) m = fmaxf(m, __shfl_xor(m, off));
    float e0 = __expf(v0 - m), e1 = __expf(v1 - m), e2 = __expf(v2 - m);
    float s = e0 + e1 + e2;
    #pragma unroll
    for (int off = 32; off; off >>= 1) s += __shfl_xor(s, off);
    float inv = 1.0f / s;
    ushort* ap = attn + px * L_;
    ap[lane] = f2bf(e0 * inv); ap[lane + 64] = f2bf(e1 * inv); ap[lane + 128] = f2bf(e2 * inv);
}

// ---------------- K8: col PV. block (w,b): M=512(c) N=96(h) K=96(g); out (b,c,w,h) ----------------
__global__ __launch_bounds__(512) void k_pvcol(const ushort* __restrict__ Vt, const ushort* __restrict__ attn,
                                               ushort* __restrict__ out1t) {
    __shared__ __align__(16) ushort Al[512 * 32];     // [c][g] 32KB linear (GLL)
    __shared__ __align__(16) ushort Bl[96 * 32];      // [h][g] 6KB linear (GLL)
    int w = blockIdx.x, bat = blockIdx.y;
    int tid = threadIdx.x, lane = tid & 63, wvid = tid >> 6;
    int wrm = wvid >> 1, wcn = wvid & 1;              // 4m x 2n, wave tile 128x48
    size_t vbase = ((size_t)bat * W_ + w) * C_ * H_;
    size_t abase = ((size_t)bat * P_ + w) * L_ + W_;
    f32x4 acc[8][3] = {};
    for (int kb = 0; kb < 96; kb += 32) {
        #pragma unroll
        for (int i = 0; i < 4; ++i) {
            int u = tid + i * 512, row = u >> 2, seg = u & 3;
            GLL16(&Vt[vbase + (size_t)row * H_ + kb + seg * 8], &Al[(size_t)u * 8]);
        }
        if (tid < 384) {
            int row = tid >> 2, seg = tid & 3;
            GLL16(&attn[abase + (size_t)row * (W_ * L_) + kb + seg * 8], &Bl[(size_t)tid * 8]);
        }
        __syncthreads();
        int rr = lane & 15, gq = lane >> 4;
        short8 fb[3];
        #pragma unroll
        for (int nt = 0; nt < 3; ++nt) fb[nt] = *(const short8*)&Bl[(wcn * 48 + nt * 16 + rr) * 32 + gq * 8];
        #pragma unroll
        for (int mt = 0; mt < 8; ++mt) {
            short8 fa = *(const short8*)&Al[(wrm * 128 + mt * 16 + rr) * 32 + gq * 8];
            #pragma unroll
            for (int nt = 0; nt < 3; ++nt)
                acc[mt][nt] = __builtin_amdgcn_mfma_f32_16x16x32_bf16(fa, fb[nt], acc[mt][nt], 0, 0, 0);
        }
        __syncthreads();
    }
    int rr = lane & 15, gq = lane >> 4;
    #pragma unroll
    for (int mt = 0; mt < 8; ++mt)
        #pragma unroll
        for (int nt = 0; nt < 3; ++nt) {
            int hh = wcn * 48 + nt * 16 + rr;
            #pragma unroll
            for (int q = 0; q < 4; ++q) {
                int c = wrm * 128 + mt * 16 + gq * 4 + q;
                out1t[((size_t)(bat * C_ + c) * W_ + w) * H_ + hh] = f2bf(acc[mt][nt][q]);
            }
        }
}

// ---------------- K7: row PV. block (h,b): M=512(c) N=96(w) K=96(v) ----------------
__global__ __launch_bounds__(512) void k_pvrow(const ushort* __restrict__ Vcm, const ushort* __restrict__ attn,
                                               ushort* __restrict__ out0) {
    __shared__ __align__(16) ushort Al[512 * 32];     // [c][v] 32KB
    __shared__ __align__(16) ushort Bl[96 * 32];      // [w][v] 6KB
    int h = blockIdx.x, bat = blockIdx.y;
    int tid = threadIdx.x, lane = tid & 63, wvid = tid >> 6;
    int wrm = wvid >> 1, wcn = wvid & 1;              // 4m x 2n, wave tile 128x48
    size_t vbase = (size_t)bat * C_ * P_ + (size_t)h * W_;
    size_t abase = ((size_t)bat * H_ + h) * W_ * L_;
    f32x4 acc[8][3] = {};
    for (int kb = 0; kb < 96; kb += 32) {
        #pragma unroll
        for (int i = 0; i < 4; ++i) {
            int u = tid + i * 512, row = u >> 2, seg = u & 3;
            GLL16(&Vcm[vbase + (size_t)row * P_ + kb + seg * 8], &Al[(size_t)u * 8]);
        }
        if (tid < 384) {
            int row = tid >> 2, seg = tid & 3;
            GLL16(&attn[abase + (size_t)row * L_ + kb + seg * 8], &Bl[(size_t)tid * 8]);
        }
        __syncthreads();
        int rr = lane & 15, gq = lane >> 4;
        short8 fb[3];
        #pragma unroll
        for (int nt = 0; nt < 3; ++nt) fb[nt] = *(const short8*)&Bl[(wcn * 48 + nt * 16 + rr) * 32 + gq * 8];
        #pragma unroll
        for (int mt = 0; mt < 8; ++mt) {
            short8 fa = *(const short8*)&Al[(wrm * 128 + mt * 16 + rr) * 32 + gq * 8];
            #pragma unroll
            for (int nt = 0; nt < 3; ++nt)
                acc[mt][nt] = __builtin_amdgcn_mfma_f32_16x16x32_bf16(fa, fb[nt], acc[mt][nt], 0, 0, 0);
        }
        __syncthreads();
    }
    int rr = lane & 15, gq = lane >> 4;
    #pragma unroll
    for (int mt = 0; mt < 8; ++mt)
        #pragma unroll
        for (int nt = 0; nt < 3; ++nt) {
            int w = wcn * 48 + nt * 16 + rr;
            #pragma unroll
            for (int q = 0; q < 4; ++q) {
                int c = wrm * 128 + mt * 16 + gq * 4 + q;
                out0[((size_t)bat * C_ + c) * P_ + (size_t)h * W_ + w] = f2bf(acc[mt][nt][q]);
            }
        }
}

// ---------------- K9: per-(b,c) plane: out = xbc + gamma*(out0 + out1t^T) ----------------
__global__ __launch_bounds__(256) void k_final(const ushort* __restrict__ xbc, const ushort* __restrict__ out0,
                                               const ushort* __restrict__ out1t, const float* __restrict__ gamma,
                                               float* __restrict__ out) {
    __shared__ ushort t[96 * 98];
    int c = blockIdx.x, bat = blockIdx.y;
    const ushort* src = out1t + ((size_t)bat * C_ + c) * P_;   // plane [w][h]
    int tid = threadIdx.x;
    for (int i = tid; i < 4608; i += 256) {
        int w = i / 48, h = (i % 48) * 2;
        ushort2 v = *(const ushort2*)&src[w * 96 + h];
        *(ushort2*)&t[w * 98 + h] = v;
    }
    __syncthreads();
    float gm = gamma[0];
    size_t base = ((size_t)bat * C_ + c) * P_;
    for (int i = tid; i < 4608; i += 256) {
        int h = i / 48, w = (i % 48) * 2;
        size_t idx = base + h * W_ + w;
        ushort2 xv = *(const ushort2*)&xbc[idx];
        ushort2 o0 = *(const ushort2*)&out0[idx];
        float2 r;
        r.x = bf2f(xv.x) + gm * (bf2f(o0.x) + bf2f(t[w * 98 + h]));
        r.y = bf2f(xv.y) + gm * (bf2f(o0.y) + bf2f(t[(w + 1) * 98 + h]));
        *(float2*)&out[idx] = r;
    }
}

extern "C" void kernel_launch(void* const* d_in, const int* in_sizes, int n_in,
                              void* d_out, int out_size, void* d_ws, size_t ws_size,
                              hipStream_t stream) {
    const float* x     = (const float*)d_in[0];
    const float* Wq    = (const float*)d_in[1];
    const float* bq    = (const float*)d_in[2];
    const float* Wk    = (const float*)d_in[3];
    const float* bk    = (const float*)d_in[4];
    const float* Wv    = (const float*)d_in[5];
    const float* bv    = (const float*)d_in[6];
    const float* gamma = (const float*)d_in[7];
    float* out = (float*)d_out;
    char* ws = (char*)d_ws;

    const size_t SZ  = (size_t)NP * C_ * 2;           // 75,497,472 B
    const size_t QKS = (size_t)NP * CQ_ * 2;          // 9,437,184 B
    // Region A: Qcm | Kcm | logits  -> later out1t (written by pvcol after all dead)
    ushort* Qcm    = (ushort*)(ws);
    ushort* Kcm    = (ushort*)(ws + QKS);
    float*  logits = (float*) (ws + 2 * QKS);
    ushort* out1t  = (ushort*)(ws);
    // Region B: xbc (bf16 x, channel-major), live proj -> final
    ushort* xbc    = (ushort*)(ws + SZ);
    // Region C: Vcm
    ushort* Vcm    = (ushort*)(ws + 2 * SZ);
    // Region D: Vt -> later out0 (pvrow runs after pvcol)
    ushort* Vt     = (ushort*)(ws + 3 * SZ);
    ushort* out0   = Vt;
    // Region E: Qb|Kb (dead after ecol) -> attn overwrites
    ushort* Qb     = (ushort*)(ws + 4 * SZ);
    ushort* Kb     = (ushort*)(ws + 4 * SZ + QKS);
    ushort* attn   = (ushort*)(ws + 4 * SZ);
    // Region W
    size_t off_wall = 4 * SZ + (size_t)NP * L_ * 2;
    ushort* Wall   = (ushort*)(ws + off_wall);
    float*  ball   = (float*) (ws + off_wall + 640 * C_ * 2);

    k_wconv  <<<dim3(1280),       dim3(256),   0, stream>>>(Wq, Wk, Wv, bq, bk, bv, Wall, ball);
    k_proj   <<<dim3(2880),       dim3(256),   0, stream>>>(x, Wall, ball, Qcm, Kcm, Vcm, xbc);
    k_qkt    <<<dim3(1152, 2),    dim3(64, 4), 0, stream>>>(Qcm, Kcm, Qb, Kb);
    k_vt     <<<dim3(512, 8),     dim3(256),   0, stream>>>(Vcm, Vt);
    k_erow   <<<dim3(96, 8),      dim3(256),   0, stream>>>(Qb, Kb, logits);
    k_ecol   <<<dim3(96, 8),      dim3(256),   0, stream>>>(Qb, Kb, logits);
    k_softmax<<<dim3(NP / 4),     dim3(256),   0, stream>>>(logits, attn);
    k_pvcol  <<<dim3(96, 8),      dim3(512),   0, stream>>>(Vt, attn, out1t);
    k_pvrow  <<<dim3(96, 8),      dim3(512),   0, stream>>>(Vcm, attn, out0);
    k_final  <<<dim3(512, 8),     dim3(256),   0, stream>>>(xbc, out0, out1t, gamma, out);
}